// Round 1
// baseline (542.319 us; speedup 1.0000x reference)
//
#include <hip/hip_runtime.h>

// Workspace layout (needs ~197 MB):
//   [0, 256K)      a_scores  fp32 [2][32][1024]   (zeroed, atomic accum)
//   [256K, 512K)   softmax w fp32 [2][32][1024]
//   [512K, 640K)   acc       fp32 [2][32][512]    (zeroed, atomic accum)
//   [1M, 2.5M)     Wt bf16   [3][512][512]  (Wt[w][n][k] = W[w][k][n])
//   [4M, 196M)     qkv bf16  [6][32768][512]  slots: q1,k1,v1,q2,k2,v2

typedef __bf16 bf16x8_t __attribute__((ext_vector_type(8)));
typedef float f32x4_t __attribute__((ext_vector_type(4)));

__device__ __forceinline__ unsigned short f2bf(float f) {
    union { float f; unsigned int u; } c; c.f = f;
    unsigned int u = c.u;
    unsigned int r = (u + 0x7FFFu + ((u >> 16) & 1u)) >> 16;  // RNE
    return (unsigned short)r;
}
__device__ __forceinline__ float bf2f(unsigned short h) {
    union { unsigned int u; float f; } c; c.u = ((unsigned int)h) << 16;
    return c.f;
}
__device__ __forceinline__ void gl2lds16(const void* g, void* l) {
    __builtin_amdgcn_global_load_lds(
        (const __attribute__((address_space(1))) void*)g,
        (__attribute__((address_space(3))) void*)l, 16, 0, 0);
}
__device__ __forceinline__ float fast_tanh(float x) {
    float e = __expf(2.f * x);                       // inf for large x -> tanh=1
    return 1.f - 2.f * __builtin_amdgcn_rcpf(e + 1.f);
}

// ---------------- Kernel 1: W [k][n] fp32 -> Wt [n][k] bf16 --------------
__global__ __launch_bounds__(256) void wconv_kernel(
    const float* __restrict__ Wq, const float* __restrict__ Wk,
    const float* __restrict__ Wv, unsigned short* __restrict__ Wt)
{
    const float* W = (blockIdx.z == 0) ? Wq : (blockIdx.z == 1) ? Wk : Wv;
    unsigned short* o = Wt + (size_t)blockIdx.z * 512 * 512;
    __shared__ unsigned short t[64][65];
    int k0 = blockIdx.x * 64, n0 = blockIdx.y * 64;
    #pragma unroll
    for (int i = 0; i < 16; ++i) {
        int idx = i * 256 + threadIdx.x;
        int r = idx >> 6, c = idx & 63;
        t[r][c] = f2bf(W[(size_t)(k0 + r) * 512 + n0 + c]);
    }
    __syncthreads();
    #pragma unroll
    for (int i = 0; i < 16; ++i) {
        int idx = i * 256 + threadIdx.x;
        int r = idx >> 6, c = idx & 63;   // r = n, c = k
        o[(size_t)(n0 + r) * 512 + k0 + c] = t[c][r];
    }
}

// ---------------- Kernel 2: QKV projection GEMM --------------------------
// C = relu(X @ W + b) -> bf16. 128x128 tile, 4 waves of 64x64, BK=32.
__global__ __launch_bounds__(256) void qkv_gemm(
    const float* __restrict__ seq1, const float* __restrict__ seq2,
    const unsigned short* __restrict__ Wt,
    const float* __restrict__ bq, const float* __restrict__ bk,
    const float* __restrict__ bv, unsigned short* __restrict__ qkv)
{
    int nt = blockIdx.x, mt = blockIdx.y, z = blockIdx.z;
    int sq = z / 3, w = z % 3;
    const float* X = sq ? seq2 : seq1;
    const unsigned short* Bt = Wt + (size_t)w * 512 * 512;
    const float* bias = (w == 0) ? bq : (w == 1) ? bk : bv;
    unsigned short* out = qkv + (size_t)z * 32768 * 512;

    __shared__ alignas(16) unsigned short As[128 * 32];
    __shared__ alignas(16) unsigned short Bs[128 * 32];

    int tid = threadIdx.x;
    int lane = tid & 63, wv = tid >> 6;
    int wm = wv >> 1, wn = wv & 1;
    int q = lane >> 4, ln = lane & 15;
    int m0 = mt * 128, n0 = nt * 128;

    f32x4_t acc[4][4] = {};

    for (int k0 = 0; k0 < 512; k0 += 32) {
        // stage A (fp32 -> bf16 via regs): 16 floats / thread
        #pragma unroll
        for (int j = 0; j < 4; ++j) {
            int idx = j * 1024 + tid * 4;
            int r = idx >> 5, kk = idx & 31;
            const float4 v = *reinterpret_cast<const float4*>(
                &X[(size_t)(m0 + r) * 512 + k0 + kk]);
            ushort4 h;
            h.x = f2bf(v.x); h.y = f2bf(v.y); h.z = f2bf(v.z); h.w = f2bf(v.w);
            *reinterpret_cast<ushort4*>(&As[r * 32 + kk]) = h;
        }
        // stage B (bf16) via global_load_lds, 2x16B per thread
        #pragma unroll
        for (int j = 0; j < 2; ++j) {
            int cbase = j * 256 + wv * 64;
            int c = cbase + lane;
            int nrow = c >> 2, kk8 = (c & 3) * 8;
            gl2lds16(&Bt[(size_t)(n0 + nrow) * 512 + k0 + kk8], &Bs[cbase * 8]);
        }
        __syncthreads();

        bf16x8_t af[4], bfr[4];
        #pragma unroll
        for (int i = 0; i < 4; ++i)
            af[i] = *reinterpret_cast<const bf16x8_t*>(
                &As[(wm * 64 + i * 16 + ln) * 32 + q * 8]);
        #pragma unroll
        for (int j = 0; j < 4; ++j)
            bfr[j] = *reinterpret_cast<const bf16x8_t*>(
                &Bs[(wn * 64 + j * 16 + ln) * 32 + q * 8]);
        #pragma unroll
        for (int i = 0; i < 4; ++i)
            #pragma unroll
            for (int j = 0; j < 4; ++j)
                acc[i][j] = __builtin_amdgcn_mfma_f32_16x16x32_bf16(
                    af[i], bfr[j], acc[i][j], 0, 0, 0);
        __syncthreads();
    }

    float bv4[4];
    #pragma unroll
    for (int j = 0; j < 4; ++j) bv4[j] = bias[n0 + wn * 64 + j * 16 + ln];
    #pragma unroll
    for (int i = 0; i < 4; ++i) {
        #pragma unroll
        for (int r = 0; r < 4; ++r) {
            int m = m0 + wm * 64 + i * 16 + q * 4 + r;
            #pragma unroll
            for (int j = 0; j < 4; ++j) {
                int n = n0 + wn * 64 + j * 16 + ln;
                float c = acc[i][j][r] + bv4[j];
                c = fmaxf(c, 0.f);
                out[(size_t)m * 512 + n] = f2bf(c);
            }
        }
    }
}

// ---------------- Kernel 3: score GEMM + tanh + row-sum ------------------
// a[which][b][s] += sum_t tanh( A[s,:] . B[t,:] ),  A=k_self, B=q_other
__global__ __launch_bounds__(256) void score_kernel(
    const unsigned short* __restrict__ qkv, float* __restrict__ a_out)
{
    int tt = blockIdx.x, st = blockIdx.y, z = blockIdx.z;
    int which = z >> 5, b = z & 31;
    const unsigned short* Am =
        qkv + ((size_t)(which ? 4 : 1) * 32768 + (size_t)b * 1024) * 512;
    const unsigned short* Bm =
        qkv + ((size_t)(which ? 0 : 3) * 32768 + (size_t)b * 1024) * 512;

    __shared__ alignas(16) unsigned short As[128 * 32];
    __shared__ alignas(16) unsigned short Bs[128 * 32];

    int tid = threadIdx.x;
    int lane = tid & 63, wv = tid >> 6;
    int wm = wv >> 1, wn = wv & 1;
    int q = lane >> 4, ln = lane & 15;
    int s0 = st * 128, t0 = tt * 128;

    f32x4_t acc[4][4] = {};

    for (int k0 = 0; k0 < 512; k0 += 32) {
        #pragma unroll
        for (int j = 0; j < 2; ++j) {
            int cbase = j * 256 + wv * 64;
            int c = cbase + lane;
            int row = c >> 2, kk8 = (c & 3) * 8;
            gl2lds16(&Am[(size_t)(s0 + row) * 512 + k0 + kk8], &As[cbase * 8]);
            gl2lds16(&Bm[(size_t)(t0 + row) * 512 + k0 + kk8], &Bs[cbase * 8]);
        }
        __syncthreads();

        bf16x8_t af[4], bfr[4];
        #pragma unroll
        for (int i = 0; i < 4; ++i)
            af[i] = *reinterpret_cast<const bf16x8_t*>(
                &As[(wm * 64 + i * 16 + ln) * 32 + q * 8]);
        #pragma unroll
        for (int j = 0; j < 4; ++j)
            bfr[j] = *reinterpret_cast<const bf16x8_t*>(
                &Bs[(wn * 64 + j * 16 + ln) * 32 + q * 8]);
        #pragma unroll
        for (int i = 0; i < 4; ++i)
            #pragma unroll
            for (int j = 0; j < 4; ++j)
                acc[i][j] = __builtin_amdgcn_mfma_f32_16x16x32_bf16(
                    af[i], bfr[j], acc[i][j], 0, 0, 0);
        __syncthreads();
    }

    #pragma unroll
    for (int i = 0; i < 4; ++i) {
        #pragma unroll
        for (int r = 0; r < 4; ++r) {
            float s = 0.f;
            #pragma unroll
            for (int j = 0; j < 4; ++j) s += fast_tanh(acc[i][j][r]);
            #pragma unroll
            for (int off = 1; off <= 8; off <<= 1) s += __shfl_xor(s, off, 64);
            if (ln == 0)
                atomicAdd(&a_out[(size_t)z * 1024 + s0 + wm * 64 + i * 16 + q * 4 + r], s);
        }
    }
}

// ---------------- Kernel 4: masked softmax over S=1024 -------------------
__global__ __launch_bounds__(256) void softmax_kernel(
    const float* __restrict__ a_in, const int* __restrict__ mask1,
    const int* __restrict__ mask2, float* __restrict__ w_out)
{
    int z = blockIdx.x, which = z >> 5, b = z & 31;
    const int* mask = (which ? mask2 : mask1) + (size_t)b * 1024;
    const float* a = a_in + (size_t)z * 1024;
    float* w = w_out + (size_t)z * 1024;
    int tid = threadIdx.x, lane = tid & 63, wv = tid >> 6;

    float vals[4];
    #pragma unroll
    for (int j = 0; j < 4; ++j) {
        int s = tid + j * 256;
        vals[j] = mask[s] ? -__builtin_inff() : a[s];
    }
    float m = fmaxf(fmaxf(vals[0], vals[1]), fmaxf(vals[2], vals[3]));
    #pragma unroll
    for (int off = 32; off; off >>= 1) m = fmaxf(m, __shfl_xor(m, off, 64));
    __shared__ float redm[4], redsum[4];
    if (lane == 0) redm[wv] = m;
    __syncthreads();
    m = fmaxf(fmaxf(redm[0], redm[1]), fmaxf(redm[2], redm[3]));

    float e[4], sum = 0.f;
    #pragma unroll
    for (int j = 0; j < 4; ++j) { e[j] = __expf(vals[j] - m); sum += e[j]; }
    #pragma unroll
    for (int off = 32; off; off >>= 1) sum += __shfl_xor(sum, off, 64);
    if (lane == 0) redsum[wv] = sum;
    __syncthreads();
    sum = redsum[0] + redsum[1] + redsum[2] + redsum[3];
    float inv = 1.f / sum;
    #pragma unroll
    for (int j = 0; j < 4; ++j) w[tid + j * 256] = e[j] * inv;
}

// --------- Kernel 5: acc[z][d] = sum_s w[s]*v[s,d] + mean_s seq[s,d] -----
__global__ __launch_bounds__(512) void wsum_kernel(
    const unsigned short* __restrict__ qkv, const float* __restrict__ w_in,
    const float* __restrict__ seq1, const float* __restrict__ seq2,
    float* __restrict__ acc)
{
    int chunk = blockIdx.x;           // 0..7, 128 rows each
    int z = blockIdx.y, which = z >> 5, b = z & 31;
    const unsigned short* V =
        qkv + ((size_t)(which ? 5 : 2) * 32768 + (size_t)b * 1024) * 512;
    const float* seq = (which ? seq2 : seq1) + (size_t)b * 1024 * 512;
    const float* w = w_in + (size_t)z * 1024;
    int d = threadIdx.x;
    float a = 0.f;
    int s0 = chunk * 128;
    for (int s = s0; s < s0 + 128; ++s) {
        a += w[s] * bf2f(V[(size_t)s * 512 + d]);
        a += seq[(size_t)s * 512 + d] * (1.f / 1024.f);
    }
    atomicAdd(&acc[(size_t)z * 512 + d], a);
}

// ---------------- Kernel 6: LayerNorm over D=512 -------------------------
__global__ __launch_bounds__(512) void ln_kernel(
    const float* __restrict__ acc, const float* __restrict__ gamma,
    const float* __restrict__ beta, float* __restrict__ out)
{
    int z = blockIdx.x, d = threadIdx.x;
    int lane = d & 63, wv = d >> 6;
    float x = acc[(size_t)z * 512 + d];
    float s = x;
    #pragma unroll
    for (int off = 32; off; off >>= 1) s += __shfl_xor(s, off, 64);
    __shared__ float red[8], red2[8];
    if (lane == 0) red[wv] = s;
    __syncthreads();
    float mu = 0.f;
    #pragma unroll
    for (int i = 0; i < 8; ++i) mu += red[i];
    mu *= (1.f / 512.f);
    float c = x - mu;
    float s2 = c * c;
    #pragma unroll
    for (int off = 32; off; off >>= 1) s2 += __shfl_xor(s2, off, 64);
    if (lane == 0) red2[wv] = s2;
    __syncthreads();
    float var = 0.f;
    #pragma unroll
    for (int i = 0; i < 8; ++i) var += red2[i];
    var *= (1.f / 512.f);
    out[(size_t)z * 512 + d] = c * __frsqrt_rn(var + 1e-5f) * gamma[d] + beta[d];
}

extern "C" void kernel_launch(void* const* d_in, const int* in_sizes, int n_in,
                              void* d_out, int out_size, void* d_ws, size_t ws_size,
                              hipStream_t stream) {
    const float* seq1 = (const float*)d_in[0];
    const float* seq2 = (const float*)d_in[1];
    const int* mask1 = (const int*)d_in[2];
    const int* mask2 = (const int*)d_in[3];
    const float* Wq = (const float*)d_in[4];
    const float* bq = (const float*)d_in[5];
    const float* Wk = (const float*)d_in[6];
    const float* bk = (const float*)d_in[7];
    const float* Wv = (const float*)d_in[8];
    const float* bv = (const float*)d_in[9];
    const float* gamma = (const float*)d_in[10];
    const float* beta = (const float*)d_in[11];
    float* out = (float*)d_out;

    char* ws = (char*)d_ws;
    float* a_sc = (float*)(ws);                      // 256 KB
    float* wsm = (float*)(ws + (256u << 10));        // 256 KB
    float* accv = (float*)(ws + (512u << 10));       // 128 KB
    unsigned short* Wt = (unsigned short*)(ws + (1u << 20));    // 1.5 MB
    unsigned short* qkv = (unsigned short*)(ws + (4u << 20));   // 192 MB

    hipMemsetAsync(ws, 0, 640u << 10, stream);  // zero a_sc + wsm + accv

    wconv_kernel<<<dim3(8, 8, 3), 256, 0, stream>>>(Wq, Wk, Wv, Wt);
    qkv_gemm<<<dim3(4, 256, 6), 256, 0, stream>>>(seq1, seq2, Wt, bq, bk, bv, qkv);
    score_kernel<<<dim3(8, 8, 64), 256, 0, stream>>>(qkv, a_sc);
    softmax_kernel<<<64, 256, 0, stream>>>(a_sc, mask1, mask2, wsm);
    wsum_kernel<<<dim3(8, 64), 512, 0, stream>>>(qkv, wsm, seq1, seq2, accv);
    ln_kernel<<<64, 512, 0, stream>>>(accv, gamma, beta, out);
}